// Round 2
// baseline (405.573 us; speedup 1.0000x reference)
//
#include <hip/hip_runtime.h>
#include <math.h>

#define BB 16
#define CC 1024
#define SS 4096
#define CCHUNKS 32
#define CPER (CC / CCHUNKS)   // 32
#define SCHUNKS 4
#define SPER (SS / SCHUNKS)   // 1024

// Kernel 1: partial channel-contraction (logit partials).
// grid = (SCHUNKS=4, CCHUNKS=32, B=16) = 2048 blocks x 256 thr = 32 waves/CU.
// Each thread owns 4 consecutive spatial positions (float4 = 16B/lane) and
// loops 32 channels fully unrolled -> many independent loads in flight.
__global__ __launch_bounds__(256) void k_partial_logits(
    const float* __restrict__ x, const float* __restrict__ w,
    float* __restrict__ partial)
{
    const int schunk = blockIdx.x;   // 0..3
    const int cchunk = blockIdx.y;   // 0..31
    const int b      = blockIdx.z;   // 0..15
    const int tid    = threadIdx.x;  // 0..255
    const int s      = schunk * SPER + tid * 4;

    const float* xb = x + (size_t)b * CC * SS + (size_t)(cchunk * CPER) * SS + s;
    const float* wc = w + cchunk * CPER;

    float4 acc = make_float4(0.f, 0.f, 0.f, 0.f);
#pragma unroll
    for (int i = 0; i < CPER; ++i) {
        const float wv = wc[i];  // uniform -> s_load, cached
        const float4 xv = *(const float4*)(xb + (size_t)i * SS);
        acc.x += xv.x * wv;
        acc.y += xv.y * wv;
        acc.z += xv.z * wv;
        acc.w += xv.w * wv;
    }
    *(float4*)(partial + ((size_t)(b * CCHUNKS + cchunk) * SS + s)) = acc;
}

// Kernel 2: reduce partials -> logits -> softmax over S per batch.
// grid = B, block = 1024 (each thread owns 4 spatial positions).
__global__ __launch_bounds__(1024) void k_softmax(
    const float* __restrict__ partial, const float* __restrict__ bias,
    float* __restrict__ attn)
{
    const int b   = blockIdx.x;
    const int tid = threadIdx.x;      // 0..1023
    const int s   = tid * 4;
    const int wave = tid >> 6;
    const int lane = tid & 63;

    float4 l = make_float4(0.f, 0.f, 0.f, 0.f);
#pragma unroll
    for (int k = 0; k < CCHUNKS; ++k) {
        const float4 p =
            *(const float4*)(partial + ((size_t)(b * CCHUNKS + k) * SS + s));
        l.x += p.x; l.y += p.y; l.z += p.z; l.w += p.w;
    }
    const float scale = 0.03125f;  // 1/sqrt(1024)
    const float bv = bias[0];
    l.x = (l.x + bv) * scale;
    l.y = (l.y + bv) * scale;
    l.z = (l.z + bv) * scale;
    l.w = (l.w + bv) * scale;

    // block max
    float m = fmaxf(fmaxf(l.x, l.y), fmaxf(l.z, l.w));
    for (int off = 32; off; off >>= 1) m = fmaxf(m, __shfl_down(m, off));
    __shared__ float redm[16];
    __shared__ float reds[16];
    if (lane == 0) redm[wave] = m;
    __syncthreads();
    if (wave == 0) {
        float v = (lane < 16) ? redm[lane] : -INFINITY;
        for (int off = 8; off; off >>= 1) v = fmaxf(v, __shfl_down(v, off));
        if (lane == 0) redm[0] = v;
    }
    __syncthreads();
    const float M = redm[0];

    float4 e;
    e.x = __expf(l.x - M);
    e.y = __expf(l.y - M);
    e.z = __expf(l.z - M);
    e.w = __expf(l.w - M);

    float ssum = (e.x + e.y) + (e.z + e.w);
    for (int off = 32; off; off >>= 1) ssum += __shfl_down(ssum, off);
    if (lane == 0) reds[wave] = ssum;
    __syncthreads();
    if (wave == 0) {
        float v = (lane < 16) ? reds[lane] : 0.f;
        for (int off = 8; off; off >>= 1) v += __shfl_down(v, off);
        if (lane == 0) reds[0] = v;
    }
    __syncthreads();
    const float inv = 1.0f / reds[0];

    float4 a = make_float4(e.x * inv, e.y * inv, e.z * inv, e.w * inv);
    *(float4*)(attn + (size_t)b * SS + s) = a;
}

// Kernel 3: focus[b,c] = sum_s x[b,c,s] * attn[b,s].
// grid = (C/8=128, B=16) = 2048 blocks x 256 thr = 32 waves/CU (fully
// resident). Each wave owns TWO channels -> 2 independent load chains.
// attn[b] staged in LDS (16 KB), reused by all 4 waves.
__global__ __launch_bounds__(256) void k_focus(
    const float* __restrict__ x, const float* __restrict__ attn,
    float* __restrict__ out)
{
    __shared__ float a_lds[SS];  // 16 KB
    const int b    = blockIdx.y;
    const int wave = threadIdx.x >> 6;
    const int lane = threadIdx.x & 63;
    const int c0   = blockIdx.x * 8 + wave * 2;

    // stage attn row (coalesced float4)
#pragma unroll
    for (int i = 0; i < 4; ++i) {
        const int idx = i * 1024 + threadIdx.x * 4;
        *(float4*)(a_lds + idx) = *(const float4*)(attn + (size_t)b * SS + idx);
    }
    __syncthreads();

    const float* xr0 = x + ((size_t)(b * CC + c0) * SS);
    const float* xr1 = xr0 + SS;
    float4 acc0 = make_float4(0.f, 0.f, 0.f, 0.f);
    float4 acc1 = make_float4(0.f, 0.f, 0.f, 0.f);
#pragma unroll
    for (int j = 0; j < 16; ++j) {
        const int s = j * 256 + lane * 4;
        const float4 xv0 = *(const float4*)(xr0 + s);
        const float4 xv1 = *(const float4*)(xr1 + s);
        const float4 av  = *(const float4*)(a_lds + s);
        acc0.x += xv0.x * av.x;
        acc0.y += xv0.y * av.y;
        acc0.z += xv0.z * av.z;
        acc0.w += xv0.w * av.w;
        acc1.x += xv1.x * av.x;
        acc1.y += xv1.y * av.y;
        acc1.z += xv1.z * av.z;
        acc1.w += xv1.w * av.w;
    }
    float v0 = (acc0.x + acc0.y) + (acc0.z + acc0.w);
    float v1 = (acc1.x + acc1.y) + (acc1.z + acc1.w);
    for (int off = 32; off; off >>= 1) {
        v0 += __shfl_down(v0, off);
        v1 += __shfl_down(v1, off);
    }
    if (lane == 0) {
        out[b * CC + c0]     = v0;
        out[b * CC + c0 + 1] = v1;
    }
}

extern "C" void kernel_launch(void* const* d_in, const int* in_sizes, int n_in,
                              void* d_out, int out_size, void* d_ws, size_t ws_size,
                              hipStream_t stream) {
    const float* x    = (const float*)d_in[0];  // [16,1024,64,64]
    const float* w    = (const float*)d_in[1];  // [1024]
    const float* bias = (const float*)d_in[2];  // [1]
    float* out = (float*)d_out;                 // [16,1024,1,1]

    float* partial = (float*)d_ws;                        // 16*32*4096 f32 = 8 MB
    float* attn    = partial + (size_t)BB * CCHUNKS * SS; // +16*4096 f32 = 256 KB

    k_partial_logits<<<dim3(SCHUNKS, CCHUNKS, BB), 256, 0, stream>>>(x, w, partial);
    k_softmax<<<BB, 1024, 0, stream>>>(partial, bias, attn);
    k_focus<<<dim3(CC / 8, BB), 256, 0, stream>>>(x, attn, out);
}

// Round 3
// 386.627 us; speedup vs baseline: 1.0490x; 1.0490x over previous
//
#include <hip/hip_runtime.h>
#include <math.h>

#define BB 16
#define CC 1024
#define SS 4096
#define SCH 16            // spatial positions per chunk
#define NCH 4             // chunks per block
#define SPB (SCH * NCH)   // 64 s per block
#define KBLK (SS / SPB)   // 64 k-blocks per batch

// Fused single-pass kernel: per block = one 64-s slice of one batch.
// Per chunk of 16 s: load x-slice to registers (8 rows x float4 per thread),
// partial logits in regs -> LDS tree -> 16-lane softmax (online, running
// m/S/alpha) -> fold the SAME registers into running numerator partials.
// x is read from HBM exactly once, never staged in LDS.
__global__ __launch_bounds__(512, 4) void k_fused(
    const float* __restrict__ x, const float* __restrict__ w,
    const float* __restrict__ bias,
    float* __restrict__ Nk, float* __restrict__ mk, float* __restrict__ sk)
{
    __shared__ float4 red4[512];   // 8 KB: per-thread logit partials
    __shared__ float4 out1[128];   // 2 KB: tree stage-1 output
    __shared__ float4 l16f4[4];    // 16 logits
    __shared__ float4 e4_lds[4];   // 16 exp weights
    __shared__ float  alpha_lds;

    const int kblk = blockIdx.x;   // 0..63
    const int b    = blockIdx.y;   // 0..15
    const int t    = threadIdx.x;  // 0..511
    const int q    = t >> 2;       // 0..127: row group (channels q+128*i)
    const int m    = t & 3;        // 0..3:  col group (s = 4m..4m+3)

    const float* xb = x + (size_t)b * CC * SS;

    float wreg[8];
#pragma unroll
    for (int i = 0; i < 8; ++i) wreg[i] = w[q + 128 * i];

    float bv = 0.f;
    if (t < 16) bv = bias[0];

    float4 np[8];
#pragma unroll
    for (int i = 0; i < 8; ++i) np[i] = make_float4(0.f, 0.f, 0.f, 0.f);
    float m_run = -1e30f, s_run = 0.f;

#pragma unroll 1
    for (int ch = 0; ch < NCH; ++ch) {
        const int s0 = kblk * SPB + ch * SCH + m * 4;

        // ---- load 8 rows x float4 (independent -> deep MLP) ----
        float4 xv[8];
#pragma unroll
        for (int i = 0; i < 8; ++i)
            xv[i] = *(const float4*)(xb + (size_t)(q + 128 * i) * SS + s0);

        // ---- partial logits in registers ----
        float4 lacc = make_float4(0.f, 0.f, 0.f, 0.f);
#pragma unroll
        for (int i = 0; i < 8; ++i) {
            lacc.x += xv[i].x * wreg[i];
            lacc.y += xv[i].y * wreg[i];
            lacc.z += xv[i].z * wreg[i];
            lacc.w += xv[i].w * wreg[i];
        }
        red4[m * 128 + q] = lacc;
        __syncthreads();                     // B1

        // ---- tree stage 1: 512 -> 128 partials ----
        if (t < 128) {
            const int mm = t >> 5, ii = t & 31;
            float4 v = red4[mm * 128 + ii];
            float4 a2 = red4[mm * 128 + ii + 32];
            float4 a3 = red4[mm * 128 + ii + 64];
            float4 a4 = red4[mm * 128 + ii + 96];
            v.x += a2.x + a3.x + a4.x;
            v.y += a2.y + a3.y + a4.y;
            v.z += a2.z + a3.z + a4.z;
            v.w += a2.w + a3.w + a4.w;
            out1[mm * 32 + ii] = v;
        }
        __syncthreads();                     // B2

        // ---- tree stage 2: 128 -> 16 logits (shuffle within 8-lane groups) ----
        if (t < 32) {
            const int mm = t >> 3, ii = t & 7;
            float4 v = out1[mm * 32 + ii];
            float4 a2 = out1[mm * 32 + ii + 8];
            float4 a3 = out1[mm * 32 + ii + 16];
            float4 a4 = out1[mm * 32 + ii + 24];
            v.x += a2.x + a3.x + a4.x;
            v.y += a2.y + a3.y + a4.y;
            v.z += a2.z + a3.z + a4.z;
            v.w += a2.w + a3.w + a4.w;
            for (int d = 4; d; d >>= 1) {
                v.x += __shfl_down(v.x, d);
                v.y += __shfl_down(v.y, d);
                v.z += __shfl_down(v.z, d);
                v.w += __shfl_down(v.w, d);
            }
            if (ii == 0) l16f4[mm] = v;      // s = 4*mm + component
        }
        __syncthreads();                     // B3

        // ---- online softmax over this chunk's 16 logits (wave 0, lanes<16) ----
        if (t < 16) {
            float l = (((const float*)l16f4)[t] + bv) * 0.03125f;
            float mc = l;
            for (int d = 8; d; d >>= 1) mc = fmaxf(mc, __shfl_xor(mc, d));
            const float mnew = fmaxf(m_run, mc);
            const float a = __expf(m_run - mnew);
            const float e = __expf(l - mnew);
            float cs = e;
            for (int d = 8; d; d >>= 1) cs += __shfl_xor(cs, d);
            s_run = s_run * a + cs;
            m_run = mnew;
            ((float*)e4_lds)[t] = e;
            if (t == 0) alpha_lds = a;
        }
        __syncthreads();                     // B4

        // ---- fold into running numerator partials (registers only) ----
        const float a = alpha_lds;
        const float4 e4 = e4_lds[m];
#pragma unroll
        for (int i = 0; i < 8; ++i) {
            np[i].x = np[i].x * a + xv[i].x * e4.x;
            np[i].y = np[i].y * a + xv[i].y * e4.y;
            np[i].z = np[i].z * a + xv[i].z * e4.z;
            np[i].w = np[i].w * a + xv[i].w * e4.w;
        }
        // no trailing barrier needed: next iter's red4 write is ordered by B2
    }

    // ---- epilogue: reduce np across the 4 m-lanes, write N_k[c] ----
#pragma unroll
    for (int i = 0; i < 8; ++i) {
        float v = (np[i].x + np[i].y) + (np[i].z + np[i].w);
        v += __shfl_down(v, 1);
        v += __shfl_down(v, 2);
        if (m == 0)
            Nk[((size_t)(b * KBLK + kblk)) * CC + q + 128 * i] = v;
    }
    if (t == 0) {
        mk[b * KBLK + kblk] = m_run;
        sk[b * KBLK + kblk] = s_run;
    }
}

// Combine across k-blocks: focus[b,c] = sum_k N_k[c] e^{m_k-M} / D.
// grid (CC/64, B), block = 64 (one wave). KBLK==64 -> one k per lane.
__global__ __launch_bounds__(64) void k_combine(
    const float* __restrict__ Nk, const float* __restrict__ mk,
    const float* __restrict__ sk, float* __restrict__ out)
{
    __shared__ float ek[KBLK];
    const int b  = blockIdx.y;
    const int c0 = blockIdx.x * 64;
    const int t  = threadIdx.x;

    const float mv = mk[b * KBLK + t];
    const float sv = sk[b * KBLK + t];
    float M = mv;
    for (int d = 32; d; d >>= 1) M = fmaxf(M, __shfl_xor(M, d));
    const float e = __expf(mv - M);
    float D = sv * e;
    for (int d = 32; d; d >>= 1) D += __shfl_xor(D, d);
    ek[t] = e / D;
    __syncthreads();

    float acc = 0.f;
    const float* Nb = Nk + (size_t)b * KBLK * CC + c0 + t;
#pragma unroll 4
    for (int k = 0; k < KBLK; ++k)
        acc += Nb[(size_t)k * CC] * ek[k];
    out[b * CC + c0 + t] = acc;
}

extern "C" void kernel_launch(void* const* d_in, const int* in_sizes, int n_in,
                              void* d_out, int out_size, void* d_ws, size_t ws_size,
                              hipStream_t stream) {
    const float* x    = (const float*)d_in[0];  // [16,1024,64,64]
    const float* w    = (const float*)d_in[1];  // [1024]
    const float* bias = (const float*)d_in[2];  // [1]
    float* out = (float*)d_out;                 // [16,1024,1,1]

    float* Nk = (float*)d_ws;                            // 16*64*1024 f32 = 4 MB
    float* mk = Nk + (size_t)BB * KBLK * CC;             // 16*64
    float* sk = mk + BB * KBLK;                          // 16*64

    k_fused<<<dim3(KBLK, BB), 512, 0, stream>>>(x, w, bias, Nk, mk, sk);
    k_combine<<<dim3(CC / 64, BB), 64, 0, stream>>>(Nk, mk, sk, out);
}

// Round 4
// 386.066 us; speedup vs baseline: 1.0505x; 1.0015x over previous
//
#include <hip/hip_runtime.h>
#include <math.h>

#define BB 16
#define CC 1024
#define SS 4096
#define SCH 16            // spatial positions per chunk
#define NCH 4             // chunks per block
#define SPB (SCH * NCH)   // 64 s per block
#define KBLK (SS / SPB)   // 64 k-blocks per batch

__device__ __forceinline__ float4 shfl_down_f4(float4 v, int d) {
    v.x = __shfl_down(v.x, d);
    v.y = __shfl_down(v.y, d);
    v.z = __shfl_down(v.z, d);
    v.w = __shfl_down(v.w, d);
    return v;
}
__device__ __forceinline__ void add4(float4& a, const float4 b) {
    a.x += b.x; a.y += b.y; a.z += b.z; a.w += b.w;
}

// Fused single-pass kernel: per block = one 64-s slice of one batch.
// Per chunk of 16 s: load x-slice to registers (8 rows x float4 per thread),
// partial logits in regs -> IN-WAVE shuffle reduce (all threads busy, no LDS
// tree) -> 512 B LDS exchange -> wave-0 cross-wave reduce + online softmax ->
// fold the SAME registers into running numerator partials.
// 2 barriers per chunk (was 4). x read from HBM exactly once.
__global__ __launch_bounds__(512, 4) void k_fused(
    const float* __restrict__ x, const float* __restrict__ w,
    const float* __restrict__ bias,
    float* __restrict__ Nk, float* __restrict__ mk, float* __restrict__ sk)
{
    __shared__ float4 wred[32];    // 512 B: per-wave logit partials (8 waves x 4 m)
    __shared__ float4 e4_lds[4];   // 16 exp weights
    __shared__ float  alpha_lds;

    const int kblk = blockIdx.x;   // 0..63
    const int b    = blockIdx.y;   // 0..15
    const int t    = threadIdx.x;  // 0..511
    const int wave = t >> 6;       // 0..7
    const int lane = t & 63;
    const int q    = t >> 2;       // 0..127: row group (channels q+128*i)
    const int m    = t & 3;        // 0..3:  col group (s = 4m..4m+3)

    const float* xb = x + (size_t)b * CC * SS;

    float wreg[8];
#pragma unroll
    for (int i = 0; i < 8; ++i) wreg[i] = w[q + 128 * i];
    const float bv = bias[0];

    float4 np[8];
#pragma unroll
    for (int i = 0; i < 8; ++i) np[i] = make_float4(0.f, 0.f, 0.f, 0.f);
    float m_run = -1e30f, s_run = 0.f;   // live on wave 0, lanes 0..3

#pragma unroll 1
    for (int ch = 0; ch < NCH; ++ch) {
        const int s0 = kblk * SPB + ch * SCH + m * 4;

        // ---- load 8 rows x float4 (independent -> deep MLP) ----
        float4 xv[8];
#pragma unroll
        for (int i = 0; i < 8; ++i)
            xv[i] = *(const float4*)(xb + (size_t)(q + 128 * i) * SS + s0);

        // ---- partial logits in registers ----
        float4 lacc = make_float4(0.f, 0.f, 0.f, 0.f);
#pragma unroll
        for (int i = 0; i < 8; ++i) {
            lacc.x += xv[i].x * wreg[i];
            lacc.y += xv[i].y * wreg[i];
            lacc.z += xv[i].z * wreg[i];
            lacc.w += xv[i].w * wreg[i];
        }

        // ---- in-wave reduce over the 16 q-slots (same m) ----
        add4(lacc, shfl_down_f4(lacc, 4));
        add4(lacc, shfl_down_f4(lacc, 8));
        add4(lacc, shfl_down_f4(lacc, 16));
        add4(lacc, shfl_down_f4(lacc, 32));
        if (lane < 4) wred[wave * 4 + lane] = lacc;   // lane == m here
        __syncthreads();                              // B1

        // ---- wave 0: cross-wave reduce (8 partials) + online softmax ----
        if (t < 32) {
            float4 v = wred[t];                       // w = t>>2, m = t&3
            add4(v, shfl_down_f4(v, 4));
            add4(v, shfl_down_f4(v, 8));
            add4(v, shfl_down_f4(v, 16));
            if (t < 4) {                              // lane == m, 4 s each
                float4 l;
                l.x = (v.x + bv) * 0.03125f;
                l.y = (v.y + bv) * 0.03125f;
                l.z = (v.z + bv) * 0.03125f;
                l.w = (v.w + bv) * 0.03125f;
                float mc = fmaxf(fmaxf(l.x, l.y), fmaxf(l.z, l.w));
                mc = fmaxf(mc, __shfl_xor(mc, 1));
                mc = fmaxf(mc, __shfl_xor(mc, 2));
                const float mnew = fmaxf(m_run, mc);
                const float a = __expf(m_run - mnew);
                float4 e;
                e.x = __expf(l.x - mnew);
                e.y = __expf(l.y - mnew);
                e.z = __expf(l.z - mnew);
                e.w = __expf(l.w - mnew);
                float cs = (e.x + e.y) + (e.z + e.w);
                cs += __shfl_xor(cs, 1);
                cs += __shfl_xor(cs, 2);
                s_run = s_run * a + cs;
                m_run = mnew;
                e4_lds[t] = e;
                if (t == 0) alpha_lds = a;
            }
        }
        __syncthreads();                              // B2

        // ---- fold into running numerator partials (registers only) ----
        const float a = alpha_lds;
        const float4 e4 = e4_lds[m];
#pragma unroll
        for (int i = 0; i < 8; ++i) {
            np[i].x = np[i].x * a + xv[i].x * e4.x;
            np[i].y = np[i].y * a + xv[i].y * e4.y;
            np[i].z = np[i].z * a + xv[i].z * e4.z;
            np[i].w = np[i].w * a + xv[i].w * e4.w;
        }
        // next chunk's wred writes are ordered by B1; e4_lds writes by B1 too
    }

    // ---- epilogue: reduce np across the 4 m-lanes, write N_k[c] ----
#pragma unroll
    for (int i = 0; i < 8; ++i) {
        float v = (np[i].x + np[i].y) + (np[i].z + np[i].w);
        v += __shfl_down(v, 1);
        v += __shfl_down(v, 2);
        if (m == 0)
            Nk[((size_t)(b * KBLK + kblk)) * CC + q + 128 * i] = v;
    }
    if (t == 0) {
        mk[b * KBLK + kblk] = m_run;
        sk[b * KBLK + kblk] = s_run;
    }
}

// Combine across k-blocks: focus[b,c] = sum_k N_k[c] e^{m_k-M} / D.
// grid (CC/64, B), block = 64 (one wave). KBLK==64 -> one k per lane.
__global__ __launch_bounds__(64) void k_combine(
    const float* __restrict__ Nk, const float* __restrict__ mk,
    const float* __restrict__ sk, float* __restrict__ out)
{
    __shared__ float ek[KBLK];
    const int b  = blockIdx.y;
    const int c0 = blockIdx.x * 64;
    const int t  = threadIdx.x;

    const float mv = mk[b * KBLK + t];
    const float sv = sk[b * KBLK + t];
    float M = mv;
    for (int d = 32; d; d >>= 1) M = fmaxf(M, __shfl_xor(M, d));
    const float e = __expf(mv - M);
    float D = sv * e;
    for (int d = 32; d; d >>= 1) D += __shfl_xor(D, d);
    ek[t] = e / D;
    __syncthreads();

    float acc = 0.f;
    const float* Nb = Nk + (size_t)b * KBLK * CC + c0 + t;
#pragma unroll 4
    for (int k = 0; k < KBLK; ++k)
        acc += Nb[(size_t)k * CC] * ek[k];
    out[b * CC + c0 + t] = acc;
}

extern "C" void kernel_launch(void* const* d_in, const int* in_sizes, int n_in,
                              void* d_out, int out_size, void* d_ws, size_t ws_size,
                              hipStream_t stream) {
    const float* x    = (const float*)d_in[0];  // [16,1024,64,64]
    const float* w    = (const float*)d_in[1];  // [1024]
    const float* bias = (const float*)d_in[2];  // [1]
    float* out = (float*)d_out;                 // [16,1024,1,1]

    float* Nk = (float*)d_ws;                            // 16*64*1024 f32 = 4 MB
    float* mk = Nk + (size_t)BB * KBLK * CC;             // 16*64
    float* sk = mk + BB * KBLK;                          // 16*64

    k_fused<<<dim3(KBLK, BB), 512, 0, stream>>>(x, w, bias, Nk, mk, sk);
    k_combine<<<dim3(CC / 64, BB), 64, 0, stream>>>(Nk, mk, sk, out);
}